// Round 2
// baseline (558.196 us; speedup 1.0000x reference)
//
#include <hip/hip_runtime.h>
#include <hip/hip_cooperative_groups.h>
#include <cstddef>
#include <cstdint>

// B=4096, IN=1024, F=512, HID=128, D=128, RH=64, OUT=1, C=10, R=16
//
// out[r,b] = x[b,:]·Wfin[r,:] + bfin[r]
//   Weff[r,f] = sum_{c,h,d} w[r,c] W2[r,h] rv[r,d] fc1_w[c,h*512+f,d]
//             + sum_{c,h}   w[r,c] W2[r,h] fc1_b[c,h*512+f]
//   Wfin[r,i] = sum_f Weff[r,f] base_w[f,i]
//   bfin[r]   = sum_f Weff[r,f] base_b[f] + b1/b2 terms via hyper linearity
//
// Coop mega-kernel v2: 2 grid.syncs (was 5), zero atomics, zero memset.
// Per-block redundant prep (w, r1, rv, W2T) from tiny inputs via L2;
// WEFF written to 8 single-writer slabs; bfin via 10 single-writer parts.

// ---- new ws layout (floats), coop path ----
#define WS2_WEFFP 0        // 8 slabs x 16 r x 512 f = 65536
#define WS2_WFIN  65536    // 16384  Wfin[r*1024+i]
#define WS2_PARTS 81920    // 10 x 16 bfin parts

// ---- legacy ws layout (floats), fallback path ----
#define WS_WT    0
#define WS_RV    160
#define WS_W2T   2208
#define WS_WEFF  4256
#define WS_WFIN  12448
#define WS_BFIN  28832
#define WS_ZERO_BEG WS_RV
#define WS_ZERO_CNT (WS_BFIN + 16 - WS_RV)

namespace cg = cooperative_groups;

// ---------------- front-MLP (flat-pointer, LDS) ----------------
__device__ __forceinline__ void front_mlp_flat(const float* __restrict__ pref,
                                               const float* __restrict__ wm1_w,
                                               const float* __restrict__ wm1_b,
                                               const float* __restrict__ wm2_w,
                                               const float* __restrict__ wm2_b,
                                               float* sh1, float* sw, float* sinv) {
  const int t = threadIdx.x;
  {
    int r = t >> 4, j = t & 15;
    float v = pref[r * 2 + 0] * wm1_w[j * 2 + 0] + pref[r * 2 + 1] * wm1_w[j * 2 + 1] + wm1_b[j];
    sh1[r * 16 + j] = fmaxf(v, 0.f);
  }
  __syncthreads();
  if (t < 160) {
    int r = t / 10, c = t % 10;
    float z = wm2_b[c];
    for (int j = 0; j < 16; ++j) z += sh1[r * 16 + j] * wm2_w[c * 16 + j];
    sw[r * 10 + c] = 1.f / (1.f + expf(-z));
  }
  __syncthreads();
  if (t < 16) {
    float s = 0.f;
    for (int c = 0; c < 10; ++c) s += sw[t * 10 + c];
    sinv[t] = 1.f / s;
  }
  __syncthreads();
  if (t < 160) {
    int r = t / 10, c = t % 10;
    sw[r * 10 + c] = sw[r * 10 + c] * sinv[r];
  }
  __syncthreads();
}

// =====================================================================
// k_all v2: 512 blocks x 256 thr, 64KB+ LDS -> 2 blocks/CU resident.
// PhaseA: per-block prep + fc1_w stream -> WEFF slabs (+parts 0..8)
// sync -> PhaseW: Wfin (33 blocks)  sync -> PhaseOUT (256 blocks)
// =====================================================================
__global__ __launch_bounds__(256, 2) void k_all(
    const float* __restrict__ x, const float* __restrict__ pref,
    const float* __restrict__ base_w, const float* __restrict__ base_b,
    const float* __restrict__ wm1_w, const float* __restrict__ wm1_b,
    const float* __restrict__ wm2_w, const float* __restrict__ wm2_b,
    const float* __restrict__ ray0_w, const float* __restrict__ ray0_b,
    const float* __restrict__ ray2_w, const float* __restrict__ ray2_b,
    const float* __restrict__ fc1_w, const float* __restrict__ fc1_b,
    const float* __restrict__ b1_w, const float* __restrict__ b1_b,
    const float* __restrict__ fc2_w, const float* __restrict__ fc2_b,
    const float* __restrict__ b2_w, const float* __restrict__ b2_b,
    float* __restrict__ ws, float* __restrict__ out) {
  __shared__ float4 sm4[4096];          // 64 KB main arena
  __shared__ float bfin_s[16];
  float* smf = (float*)sm4;
  // ---- phase-A arena (floats) ----
  float* sw   = smf;            // [0,160)    sw[r*10+c]
  float* sinv = smf + 160;      // [160,176)
  float* sh1  = smf + 176;      // [176,432)
  float* rvl  = smf + 432;      // [432,2544)   rv[16][132]
  float* w2t  = smf + 2544;     // [2544,4720)  W2T[128][17]
  float* X    = smf + 4720;     // [4720,8880)  union: r1s(1040)/stage(4160)/scoef(2560)
  float* bfred= smf + 8880;     // [8880,8944)

  cg::grid_group grid = cg::this_grid();
  const int t = threadIdx.x;
  const int blk = blockIdx.x;
  const int wid = t >> 6, lane = t & 63, l32 = lane & 31;

  // ================= PHASE A =================
  // front MLP -> sw
  front_mlp_flat(pref, wm1_w, wm1_b, wm2_w, wm2_b, sh1, sw, sinv);

  // r1[16][64] in X (padded 65)
  {
    float* r1s = X;
    for (int it = t; it < 1024; it += 256) {
      int r = it >> 6, o = it & 63;
      float m0 = 0.f, m1 = 0.f, rb = 0.f;
      for (int c = 0; c < 10; ++c) {
        float wv = sw[r * 10 + c];
        m0 += wv * ray0_w[(c * 64 + o) * 2 + 0];
        m1 += wv * ray0_w[(c * 64 + o) * 2 + 1];
        rb += wv * ray0_b[c * 64 + o];
      }
      float v = pref[r * 2 + 0] * m0 + pref[r * 2 + 1] * m1 + rb;
      r1s[r * 65 + o] = fmaxf(v, 0.f);
    }
    __syncthreads();
    // rv[r][d] = sum_c sw[r][c]*(ray2_w[c,d,:]·r1[r,:] + ray2_b[c,d])
    const int d = t & 127, rh = (t >> 7) * 8;
    float accv[8];
#pragma unroll
    for (int j = 0; j < 8; ++j) accv[j] = 0.f;
    for (int c = 0; c < 10; ++c) {
      const float4* row4 = (const float4*)(ray2_w + (size_t)(c * 128 + d) * 64);
      float dtmp[8];
#pragma unroll
      for (int j = 0; j < 8; ++j) dtmp[j] = 0.f;
#pragma unroll
      for (int k4 = 0; k4 < 16; ++k4) {
        float4 rw = row4[k4];
#pragma unroll
        for (int rr = 0; rr < 8; ++rr) {
          const float* rr1 = r1s + (rh + rr) * 65 + k4 * 4;
          dtmp[rr] += rw.x * rr1[0] + rw.y * rr1[1] + rw.z * rr1[2] + rw.w * rr1[3];
        }
      }
      float rb = ray2_b[c * 128 + d];
#pragma unroll
      for (int rr = 0; rr < 8; ++rr)
        accv[rr] += sw[(rh + rr) * 10 + c] * (dtmp[rr] + rb);
    }
#pragma unroll
    for (int rr = 0; rr < 8; ++rr) rvl[(rh + rr) * 132 + d] = accv[rr];
  }
  __syncthreads();   // rvl ready; r1s dead

  // W2T[h][r] = sum_c sw[r][c]*(fc2_w[c,h,:]·rv[r,:] + fc2_b[c,h])
  {
    float* stg = X;                       // [32][130]
    const int hl = t >> 3;                // 0..31
    const int rg = (t & 7) * 2;           // r base (2 r per thread)
    float accw[4][2];
#pragma unroll
    for (int a = 0; a < 4; ++a) { accw[a][0] = 0.f; accw[a][1] = 0.f; }
    for (int c = 0; c < 10; ++c) {
      for (int ch = 0; ch < 4; ++ch) {
        __syncthreads();
        const float4* src = (const float4*)(fc2_w + ((size_t)c * 128 + ch * 32) * 128);
#pragma unroll
        for (int k = 0; k < 4; ++k) {
          int j = t + 256 * k;            // 0..1023 float4
          int h_loc = j >> 5, dof = (j & 31) * 4;
          float4 v = src[j];
          float* dst = stg + h_loc * 130 + dof;
          ((float2*)dst)[0] = make_float2(v.x, v.y);
          ((float2*)dst)[1] = make_float2(v.z, v.w);
        }
        __syncthreads();
        float dt0 = 0.f, dt1 = 0.f;
        const float2* srow = (const float2*)(stg + hl * 130);
        const float2* rv0 = (const float2*)(rvl + (rg + 0) * 132);
        const float2* rv1 = (const float2*)(rvl + (rg + 1) * 132);
#pragma unroll 8
        for (int d2 = 0; d2 < 64; ++d2) {
          float2 fv = srow[d2];
          float2 a0 = rv0[d2], a1 = rv1[d2];
          dt0 += fv.x * a0.x + fv.y * a0.y;
          dt1 += fv.x * a1.x + fv.y * a1.y;
        }
        int h = ch * 32 + hl;
        float fb = fc2_b[c * 128 + h];
        accw[ch][0] += sw[(rg + 0) * 10 + c] * (dt0 + fb);
        accw[ch][1] += sw[(rg + 1) * 10 + c] * (dt1 + fb);
      }
    }
#pragma unroll
    for (int ch = 0; ch < 4; ++ch) {
      int h = ch * 32 + hl;
      w2t[h * 17 + rg] = accw[ch][0];
      w2t[h * 17 + rg + 1] = accw[ch][1];
    }
  }
  __syncthreads();   // w2t ready; stage dead

  // scoef for this block's ch-chunk
  float* scoef = X;
  const int cc = blk >> 6;
  const int ch0 = cc * 160;
  const int fp = (blk & 63) * 4 + wid;    // 0..255
  for (int i = t; i < 2560; i += 256) {
    int chl = i >> 4, r = i & 15;
    int ch = ch0 + chl;
    scoef[i] = sw[r * 10 + (ch >> 7)] * w2t[(ch & 127) * 17 + r];
  }
  float4 rv[16];
#pragma unroll
  for (int r = 0; r < 16; ++r) rv[r] = *(const float4*)&rvl[r * 132 + l32 * 4];
  __syncthreads();   // scoef ready

  // ---- fc1_w stream: 160 ch, depth-8 VGPR pipeline ----
  {
    float acc[16];
#pragma unroll
    for (int r = 0; r < 16; ++r) acc[r] = 0.f;
    const float4* p = (const float4*)fc1_w + (size_t)ch0 * 16384 + fp * 64 + lane;
    float4 buf[8];
#pragma unroll
    for (int j = 0; j < 8; ++j) buf[j] = p[(size_t)j * 16384];
    for (int g = 0; g < 20; ++g) {
#pragma unroll
      for (int k = 0; k < 8; ++k) {
        const int chl = g * 8 + k;
        float4 cur = buf[k];
        int nxt = chl + 8; if (nxt > 159) nxt = 159;
        buf[k] = p[(size_t)nxt * 16384];
        const float4* cf = (const float4*)(scoef + chl * 16);
        float4 c0 = cf[0], c1 = cf[1], c2 = cf[2], c3 = cf[3];
        float cw[16] = {c0.x, c0.y, c0.z, c0.w, c1.x, c1.y, c1.z, c1.w,
                        c2.x, c2.y, c2.z, c2.w, c3.x, c3.y, c3.z, c3.w};
#pragma unroll
        for (int r = 0; r < 16; ++r) {
          float tt = cur.x * rv[r].x + cur.y * rv[r].y + cur.z * rv[r].z + cur.w * rv[r].w;
          acc[r] = fmaf(cw[r], tt, acc[r]);
        }
      }
    }
    // fc1_b fold, distributed across the 32-lane reduce half
    const int f = fp * 2 + (lane >> 5);
#pragma unroll
    for (int j = 0; j < 5; ++j) {
      int chl = l32 + j * 32;
      float fb = fc1_b[(size_t)(ch0 + chl) * 512 + f];
#pragma unroll
      for (int r = 0; r < 16; ++r) acc[r] = fmaf(scoef[chl * 16 + r], fb, acc[r]);
    }
#pragma unroll
    for (int m = 1; m <= 16; m <<= 1) {
#pragma unroll
      for (int r = 0; r < 16; ++r) acc[r] += __shfl_xor(acc[r], m, 64);
    }
    if (l32 == 0) {
#pragma unroll
      for (int r = 0; r < 16; ++r)
        ws[WS2_WEFFP + cc * 8192 + r * 512 + f] = acc[r];   // single-writer slab
    }
  }
  __syncthreads();   // scoef free for extras

  // ---- extras: bfin parts 0..8 (single-writer) ----
  if (blk < 8) {
    // part blk: sum over ch in [blk*160, +160): coef*(b1_w[ch,:]·rv)
    const int ch0b = blk * 160;
    for (int i = t; i < 2560; i += 256) {
      int chl = i >> 4, r = i & 15;
      int ch = ch0b + chl;
      scoef[i] = sw[r * 10 + (ch >> 7)] * w2t[(ch & 127) * 17 + r];
    }
    __syncthreads();
    float2 rv2[16];
#pragma unroll
    for (int r = 0; r < 16; ++r) rv2[r] = *(const float2*)&rvl[r * 132 + lane * 2];
    float a2[16];
#pragma unroll
    for (int r = 0; r < 16; ++r) a2[r] = 0.f;
    const int chl0 = wid * 40;
    const float2* q = (const float2*)b1_w + (size_t)(ch0b + chl0) * 64 + lane;
    float2 b2buf[4];
#pragma unroll
    for (int j = 0; j < 4; ++j) b2buf[j] = q[(size_t)j * 64];
    for (int g = 0; g < 10; ++g) {
#pragma unroll
      for (int k = 0; k < 4; ++k) {
        const int it = g * 4 + k;
        float2 cur = b2buf[k];
        int nxt = it + 4; if (nxt > 39) nxt = 39;
        b2buf[k] = q[(size_t)nxt * 64];
        const float4* cf = (const float4*)(scoef + (chl0 + it) * 16);
        float4 c0 = cf[0], c1 = cf[1], c2 = cf[2], c3 = cf[3];
        float cw[16] = {c0.x, c0.y, c0.z, c0.w, c1.x, c1.y, c1.z, c1.w,
                        c2.x, c2.y, c2.z, c2.w, c3.x, c3.y, c3.z, c3.w};
#pragma unroll
        for (int r = 0; r < 16; ++r)
          a2[r] = fmaf(cw[r], cur.x * rv2[r].x + cur.y * rv2[r].y, a2[r]);
      }
    }
#pragma unroll
    for (int m = 1; m <= 32; m <<= 1) {
#pragma unroll
      for (int r = 0; r < 16; ++r) a2[r] += __shfl_xor(a2[r], m, 64);
    }
    if (lane == 0) {
#pragma unroll
      for (int r = 0; r < 16; ++r) bfred[wid * 16 + r] = a2[r];
    }
    __syncthreads();
    if (t < 16)
      ws[WS2_PARTS + blk * 16 + t] = bfred[t] + bfred[16 + t] + bfred[32 + t] + bfred[48 + t];
  } else if (blk == 8) {
    // part 8: coef·b1_b + (w·rv)·b2_w + w·b2_b
    float a2[16];
#pragma unroll
    for (int r = 0; r < 16; ++r) a2[r] = 0.f;
    for (int i = t; i < 1280; i += 256) {
      int c = i >> 7, h = i & 127;
      float v = b1_b[c * 128 + h];
#pragma unroll
      for (int r = 0; r < 16; ++r)
        a2[r] = fmaf(sw[r * 10 + c] * w2t[h * 17 + r], v, a2[r]);
    }
    for (int i = t; i < 1280; i += 256) {
      int c = i >> 7, d = i & 127;
      float v = b2_w[c * 128 + d];
#pragma unroll
      for (int r = 0; r < 16; ++r)
        a2[r] = fmaf(sw[r * 10 + c] * rvl[r * 132 + d], v, a2[r]);
    }
    if (t < 10) {
      float v = b2_b[t];
#pragma unroll
      for (int r = 0; r < 16; ++r) a2[r] = fmaf(sw[r * 10 + t], v, a2[r]);
    }
#pragma unroll
    for (int m = 1; m <= 32; m <<= 1) {
#pragma unroll
      for (int r = 0; r < 16; ++r) a2[r] += __shfl_xor(a2[r], m, 64);
    }
    if (lane == 0) {
#pragma unroll
      for (int r = 0; r < 16; ++r) bfred[wid * 16 + r] = a2[r];
    }
    __syncthreads();
    if (t < 16)
      ws[WS2_PARTS + 8 * 16 + t] = bfred[t] + bfred[16 + t] + bfred[32 + t] + bfred[48 + t];
  }
  grid.sync();   // ---- sync 1: all slabs + parts 0..8 visible ----

  // ================= PHASE W =================
  if (blk < 32) {
    float* weffl = smf;          // 8192: summed WEFF[16][512]
    float* red   = smf + 8192;   // 4096
    for (int idx = t; idx < 8192; idx += 256) {
      float s = 0.f;
#pragma unroll
      for (int c2 = 0; c2 < 8; ++c2) s += ws[WS2_WEFFP + c2 * 8192 + idx];
      weffl[idx] = s;
    }
    __syncthreads();
    const int il = t & 31, fg = t >> 5;   // 8 f-groups of 64
    const int i = blk * 32 + il;
    float a4[16];
#pragma unroll
    for (int r = 0; r < 16; ++r) a4[r] = 0.f;
    const int f0 = fg * 64;
    for (int f = f0; f < f0 + 64; ++f) {
      float bw = base_w[(size_t)f * 1024 + i];
#pragma unroll
      for (int r = 0; r < 16; ++r) a4[r] = fmaf(weffl[r * 512 + f], bw, a4[r]);
    }
#pragma unroll
    for (int r = 0; r < 16; ++r) red[fg * 512 + il * 16 + r] = a4[r];
    __syncthreads();
    for (int o = t; o < 512; o += 256) {
      int ir = o >> 4, r = o & 15;
      float s = 0.f;
#pragma unroll
      for (int fg2 = 0; fg2 < 8; ++fg2) s += red[fg2 * 512 + ir * 16 + r];
      ws[WS2_WFIN + r * 1024 + blk * 32 + ir] = s;
    }
  } else if (blk == 32) {
    if (t < 64) {
      float a2[16];
#pragma unroll
      for (int r = 0; r < 16; ++r) a2[r] = 0.f;
      for (int f = t; f < 512; f += 64) {
        float bb = base_b[f];
#pragma unroll
        for (int r = 0; r < 16; ++r) {
          float s = 0.f;
#pragma unroll
          for (int c2 = 0; c2 < 8; ++c2) s += ws[WS2_WEFFP + c2 * 8192 + r * 512 + f];
          a2[r] = fmaf(s, bb, a2[r]);
        }
      }
#pragma unroll
      for (int m = 1; m <= 32; m <<= 1) {
#pragma unroll
        for (int r = 0; r < 16; ++r) a2[r] += __shfl_xor(a2[r], m, 64);
      }
      if (t == 0) {
#pragma unroll
        for (int r = 0; r < 16; ++r) ws[WS2_PARTS + 9 * 16 + r] = a2[r];
      }
    }
  }
  grid.sync();   // ---- sync 2: Wfin + part 9 visible ----

  // ================= PHASE OUT =================
  if (blk < 256) {
    if (t < 16) {
      float s = 0.f;
#pragma unroll
      for (int sl = 0; sl < 10; ++sl) s += ws[WS2_PARTS + sl * 16 + t];
      bfin_s[t] = s;
    }
    float4* wfs = sm4;                    // 64 KB: Wfin as [r*256 + i4]
    const float4* wf4 = (const float4*)(ws + WS2_WFIN);
#pragma unroll
    for (int k = 0; k < 16; ++k) wfs[t + 256 * k] = wf4[t + 256 * k];
    __syncthreads();

    const int b0 = blk * 16;
    const int bp = t >> 5;
    const int isub = t & 31;
    const int bA = b0 + bp * 2;
    const float* xa = x + (size_t)bA * 1024;
    const float* xb = xa + 1024;
    float acc0[16], acc1[16];
#pragma unroll
    for (int r = 0; r < 16; ++r) { acc0[r] = 0.f; acc1[r] = 0.f; }

    for (int chunk = 0; chunk < 4; ++chunk) {
#pragma unroll
      for (int j = 0; j < 2; ++j) {
        const int off = chunk * 256 + j * 128 + isub * 4;
        float4 xv0 = *(const float4*)&xa[off];
        float4 xv1 = *(const float4*)&xb[off];
        const float4* wrow = wfs + chunk * 64 + j * 32 + isub;
#pragma unroll
        for (int r = 0; r < 16; ++r) {
          float4 w = wrow[r * 256];
          acc0[r] += xv0.x * w.x + xv0.y * w.y + xv0.z * w.z + xv0.w * w.w;
          acc1[r] += xv1.x * w.x + xv1.y * w.y + xv1.z * w.z + xv1.w * w.w;
        }
      }
    }
#pragma unroll
    for (int m = 1; m <= 16; m <<= 1) {
#pragma unroll
      for (int r = 0; r < 16; ++r) {
        acc0[r] += __shfl_xor(acc0[r], m, 64);
        acc1[r] += __shfl_xor(acc1[r], m, 64);
      }
    }
    if (isub == 0) {
#pragma unroll
      for (int r = 0; r < 16; ++r) {
        float bf = bfin_s[r];
        float v0 = acc0[r] + bf;
        float v1 = acc1[r] + bf;
        out[r * 4096 + bA] = 1.f / (1.f + expf(-v0));
        out[r * 4096 + bA + 1] = 1.f / (1.f + expf(-v1));
        out[65536 + r * 4096 + bA] = v0;
        out[65536 + r * 4096 + bA + 1] = v1;
      }
    }
  }
}

// =====================================================================
// Legacy 6-dispatch path — runtime fallback only (proven correct).
// =====================================================================
__device__ __forceinline__ void front_mlp(const float* __restrict__ pref,
                                          const float* __restrict__ wm1_w,
                                          const float* __restrict__ wm1_b,
                                          const float* __restrict__ wm2_w,
                                          const float* __restrict__ wm2_b,
                                          float (*sh1)[16], float (*sw)[10],
                                          float* sinv) {
  const int t = threadIdx.x;
  {
    int r = t >> 4, j = t & 15;
    float v = pref[r * 2 + 0] * wm1_w[j * 2 + 0] + pref[r * 2 + 1] * wm1_w[j * 2 + 1] + wm1_b[j];
    sh1[r][j] = fmaxf(v, 0.f);
  }
  __syncthreads();
  if (t < 160) {
    int r = t / 10, c = t % 10;
    float z = wm2_b[c];
    for (int j = 0; j < 16; ++j) z += sh1[r][j] * wm2_w[c * 16 + j];
    sw[r][c] = 1.f / (1.f + expf(-z));
  }
  __syncthreads();
  if (t < 16) {
    float s = 0.f;
    for (int c = 0; c < 10; ++c) s += sw[t][c];
    sinv[t] = 1.f / s;
  }
  __syncthreads();
  if (t < 160) {
    int r = t / 10, c = t % 10;
    sw[r][c] = sw[r][c] * sinv[r];
  }
  __syncthreads();
}

__global__ __launch_bounds__(256) void k_stage1(
    const float* __restrict__ pref, const float* __restrict__ wm1_w,
    const float* __restrict__ wm1_b, const float* __restrict__ wm2_w,
    const float* __restrict__ wm2_b, const float* __restrict__ ray0_w,
    const float* __restrict__ ray0_b, const float* __restrict__ ray2_w,
    const float* __restrict__ ray2_b, const float* __restrict__ fc2_b,
    float* __restrict__ ws) {
  __shared__ float sh1[16][16];
  __shared__ float sw[16][10];
  __shared__ float sinv[16];
  __shared__ float r1s[16][65];
  const int t = threadIdx.x;
  front_mlp(pref, wm1_w, wm1_b, wm2_w, wm2_b, sh1, sw, sinv);
  for (int it = t; it < 1024; it += 256) {
    int r = it >> 6, o = it & 63;
    float m0 = 0.f, m1 = 0.f, rb = 0.f;
    for (int c = 0; c < 10; ++c) {
      float wv = sw[r][c];
      m0 += wv * ray0_w[(c * 64 + o) * 2 + 0];
      m1 += wv * ray0_w[(c * 64 + o) * 2 + 1];
      rb += wv * ray0_b[c * 64 + o];
    }
    float v = pref[r * 2 + 0] * m0 + pref[r * 2 + 1] * m1 + rb;
    r1s[r][o] = fmaxf(v, 0.f);
  }
  __syncthreads();
  const int pair = blockIdx.x * 16 + (t >> 4);
  const int r = t & 15;
  const float* row = ray2_w + (size_t)pair * 64;
  const float* r1r = r1s[r];
  float dot = 0.f;
#pragma unroll
  for (int k = 0; k < 64; ++k) dot += row[k] * r1r[k];
  int c = pair >> 7, d = pair & 127;
  atomicAdd(&ws[WS_RV + r * 128 + d], sw[r][c] * dot);

  if (blockIdx.x == 0) {
    if (t < 160) ws[WS_WT + t] = sw[t & 15][t >> 4];
    for (int i = t; i < 2048; i += 256) {
      int rr = i >> 7, dd = i & 127;
      float s = 0.f;
      for (int cc = 0; cc < 10; ++cc) s += sw[rr][cc] * ray2_b[cc * 128 + dd];
      atomicAdd(&ws[WS_RV + i], s);
    }
  } else if (blockIdx.x == 1) {
    for (int i = t; i < 2048; i += 256) {
      int h = i >> 4, rr = i & 15;
      float s = 0.f;
      for (int cc = 0; cc < 10; ++cc) s += sw[rr][cc] * fc2_b[cc * 128 + h];
      atomicAdd(&ws[WS_W2T + i], s);
    }
  }
}

__global__ __launch_bounds__(256) void k_stage2(const float* __restrict__ fc2_w,
                                                float* __restrict__ ws) {
  const int t = threadIdx.x;
  const int lane = t & 63;
  const int wv = blockIdx.x * 4 + (t >> 6);
  float2 rv2[16];
#pragma unroll
  for (int r = 0; r < 16; ++r) rv2[r] = *(const float2*)&ws[WS_RV + r * 128 + lane * 2];
  for (int q = 0; q < 4; ++q) {
    int rid = wv * 4 + q;
    int c = rid >> 7, h = rid & 127;
    float2 a = *(const float2*)&fc2_w[(size_t)rid * 128 + lane * 2];
    float u[16];
#pragma unroll
    for (int r = 0; r < 16; ++r) u[r] = a.x * rv2[r].x + a.y * rv2[r].y;
#pragma unroll
    for (int m = 1; m <= 32; m <<= 1) {
#pragma unroll
      for (int r = 0; r < 16; ++r) u[r] += __shfl_xor(u[r], m, 64);
    }
    if (lane == 0) {
#pragma unroll
      for (int r = 0; r < 16; ++r)
        atomicAdd(&ws[WS_W2T + h * 16 + r], u[r] * ws[WS_WT + c * 16 + r]);
    }
  }
}

__global__ __launch_bounds__(256, 3) void k_main(
    const float* __restrict__ fc1_w, const float* __restrict__ fc1_b,
    const float* __restrict__ b1_w, const float* __restrict__ b1_b,
    const float* __restrict__ b2_w, const float* __restrict__ b2_b,
    float* __restrict__ ws) {
  __shared__ float scoef[2560];
  __shared__ float bfred[4][16];
  const int blk = blockIdx.x;
  const int t = threadIdx.x;

  if (blk < 2048) {
    const int wid = t >> 6, lane = t & 63, l32 = lane & 31;
    const int ch0 = (blk >> 6) * 40;
    const int fp = (blk & 63) * 4 + wid;
    for (int i = t; i < 640; i += 256) {
      int chl = i >> 4, r = i & 15;
      int ch = ch0 + chl, c = ch >> 7, h = ch & 127;
      scoef[i] = ws[WS_WT + c * 16 + r] * ws[WS_W2T + h * 16 + r];
    }
    float4 rv[16];
#pragma unroll
    for (int r = 0; r < 16; ++r) rv[r] = *(const float4*)&ws[WS_RV + r * 128 + l32 * 4];
    __syncthreads();

    float acc[16];
#pragma unroll
    for (int r = 0; r < 16; ++r) acc[r] = 0.f;

    const float4* p = (const float4*)fc1_w + (size_t)ch0 * 16384 + fp * 64 + lane;

    float4 buf[8];
#pragma unroll
    for (int j = 0; j < 8; ++j) buf[j] = p[(size_t)j * 16384];

    for (int g = 0; g < 5; ++g) {
#pragma unroll
      for (int k = 0; k < 8; ++k) {
        const int chl = g * 8 + k;
        float4 cur = buf[k];
        int nxt = chl + 8; if (nxt > 39) nxt = 39;
        buf[k] = p[(size_t)nxt * 16384];
        const float4* cf = (const float4*)(scoef + chl * 16);
        float4 c0 = cf[0], c1 = cf[1], c2 = cf[2], c3 = cf[3];
        float cw[16] = {c0.x, c0.y, c0.z, c0.w, c1.x, c1.y, c1.z, c1.w,
                        c2.x, c2.y, c2.z, c2.w, c3.x, c3.y, c3.z, c3.w};
#pragma unroll
        for (int r = 0; r < 16; ++r) {
          float tt = cur.x * rv[r].x + cur.y * rv[r].y + cur.z * rv[r].z + cur.w * rv[r].w;
          acc[r] = fmaf(cw[r], tt, acc[r]);
        }
      }
    }

#pragma unroll
    for (int m = 1; m <= 16; m <<= 1) {
#pragma unroll
      for (int r = 0; r < 16; ++r) acc[r] += __shfl_xor(acc[r], m, 64);
    }
    if (l32 == 0) {
      const int f = fp * 2 + (lane >> 5);
#pragma unroll
      for (int r = 0; r < 16; ++r) atomicAdd(&ws[WS_WEFF + r * 512 + f], acc[r]);
    }
  } else if (blk < 2064) {
    const int bb = blk - 2048;
    const int f = (bb & 1) * 256 + t;
    const int ch0 = (bb >> 1) * 160;
    for (int i = t; i < 2560; i += 256) {
      int chl = i >> 4, r = i & 15;
      int ch = ch0 + chl, c = ch >> 7, h = ch & 127;
      scoef[i] = ws[WS_WT + c * 16 + r] * ws[WS_W2T + h * 16 + r];
    }
    __syncthreads();
    float acc[16];
#pragma unroll
    for (int r = 0; r < 16; ++r) acc[r] = 0.f;
    const float* q = fc1_b + (size_t)ch0 * 512 + f;
    float b4[4];
#pragma unroll
    for (int j = 0; j < 4; ++j) b4[j] = q[(size_t)j * 512];
    for (int g = 0; g < 40; ++g) {
#pragma unroll
      for (int k = 0; k < 4; ++k) {
        const int it = g * 4 + k;
        float xv = b4[k];
        int nxt = it + 4; if (nxt > 159) nxt = 159;
        b4[k] = q[(size_t)nxt * 512];
        const float4* cf = (const float4*)(scoef + it * 16);
        float4 c0 = cf[0], c1 = cf[1], c2 = cf[2], c3 = cf[3];
        float cw[16] = {c0.x, c0.y, c0.z, c0.w, c1.x, c1.y, c1.z, c1.w,
                        c2.x, c2.y, c2.z, c2.w, c3.x, c3.y, c3.z, c3.w};
#pragma unroll
        for (int r = 0; r < 16; ++r) acc[r] = fmaf(cw[r], xv, acc[r]);
      }
    }
#pragma unroll
    for (int r = 0; r < 16; ++r) atomicAdd(&ws[WS_WEFF + r * 512 + f], acc[r]);
  } else if (blk < 2072) {
    const int hb = blk - 2064;
    const int wid = t >> 6, lane = t & 63;
    const int ch0b = hb * 160;
    for (int i = t; i < 2560; i += 256) {
      int chl = i >> 4, r = i & 15;
      int ch = ch0b + chl, c = ch >> 7, h = ch & 127;
      scoef[i] = ws[WS_WT + c * 16 + r] * ws[WS_W2T + h * 16 + r];
    }
    __syncthreads();
    float2 rv2[16];
#pragma unroll
    for (int r = 0; r < 16; ++r) rv2[r] = *(const float2*)&ws[WS_RV + r * 128 + lane * 2];
    float acc[16];
#pragma unroll
    for (int r = 0; r < 16; ++r) acc[r] = 0.f;
    const int chl0 = wid * 40;
    const float2* q = (const float2*)b1_w + (size_t)(ch0b + chl0) * 64 + lane;
    float2 b2buf[4];
#pragma unroll
    for (int j = 0; j < 4; ++j) b2buf[j] = q[(size_t)j * 64];
    for (int g = 0; g < 10; ++g) {
#pragma unroll
      for (int k = 0; k < 4; ++k) {
        const int it = g * 4 + k;
        float2 cur = b2buf[k];
        int nxt = it + 4; if (nxt > 39) nxt = 39;
        b2buf[k] = q[(size_t)nxt * 64];
        const float4* cf = (const float4*)(scoef + (chl0 + it) * 16);
        float4 c0 = cf[0], c1 = cf[1], c2 = cf[2], c3 = cf[3];
        float cw[16] = {c0.x, c0.y, c0.z, c0.w, c1.x, c1.y, c1.z, c1.w,
                        c2.x, c2.y, c2.z, c2.w, c3.x, c3.y, c3.z, c3.w};
#pragma unroll
        for (int r = 0; r < 16; ++r)
          acc[r] = fmaf(cw[r], cur.x * rv2[r].x + cur.y * rv2[r].y, acc[r]);
      }
    }
#pragma unroll
    for (int m = 1; m <= 32; m <<= 1) {
#pragma unroll
      for (int r = 0; r < 16; ++r) acc[r] += __shfl_xor(acc[r], m, 64);
    }
    if (lane == 0) {
#pragma unroll
      for (int r = 0; r < 16; ++r) bfred[wid][r] = acc[r];
    }
    __syncthreads();
    if (t < 16)
      atomicAdd(&ws[WS_BFIN + t], bfred[0][t] + bfred[1][t] + bfred[2][t] + bfred[3][t]);
  } else {
    const int wid = t >> 6, lane = t & 63;
    float acc[16];
#pragma unroll
    for (int r = 0; r < 16; ++r) acc[r] = 0.f;
    for (int i = t; i < 1280; i += 256) {
      int c = i >> 7, h = i & 127;
      float v = b1_b[c * 128 + h];
#pragma unroll
      for (int r = 0; r < 16; ++r)
        acc[r] = fmaf(ws[WS_WT + c * 16 + r] * ws[WS_W2T + h * 16 + r], v, acc[r]);
    }
    for (int i = t; i < 1280; i += 256) {
      int c = i >> 7, d = i & 127;
      float v = b2_w[c * 128 + d];
#pragma unroll
      for (int r = 0; r < 16; ++r)
        acc[r] = fmaf(ws[WS_WT + c * 16 + r] * ws[WS_RV + r * 128 + d], v, acc[r]);
    }
    if (t < 10) {
      float v = b2_b[t];
#pragma unroll
      for (int r = 0; r < 16; ++r) acc[r] = fmaf(ws[WS_WT + t * 16 + r], v, acc[r]);
    }
#pragma unroll
    for (int m = 1; m <= 32; m <<= 1) {
#pragma unroll
      for (int r = 0; r < 16; ++r) acc[r] += __shfl_xor(acc[r], m, 64);
    }
    if (lane == 0) {
#pragma unroll
      for (int r = 0; r < 16; ++r) bfred[wid][r] = acc[r];
    }
    __syncthreads();
    if (t < 16)
      atomicAdd(&ws[WS_BFIN + t], bfred[0][t] + bfred[1][t] + bfred[2][t] + bfred[3][t]);
  }
}

__global__ __launch_bounds__(256) void k_wfin(const float* __restrict__ base_w,
                                              const float* __restrict__ base_b,
                                              float* __restrict__ ws) {
  const int t = threadIdx.x;
  const int blk = blockIdx.x;
  const int i = (blk & 3) * 256 + t;
  const int f0 = (blk >> 2) * 16;
  const float* WEFF = ws + WS_WEFF;
  float acc[16];
#pragma unroll
  for (int r = 0; r < 16; ++r) acc[r] = 0.f;
#pragma unroll 4
  for (int f = f0; f < f0 + 16; ++f) {
    float bw = base_w[(size_t)f * 1024 + i];
#pragma unroll
    for (int r = 0; r < 16; ++r) acc[r] = fmaf(WEFF[r * 512 + f], bw, acc[r]);
  }
#pragma unroll
  for (int r = 0; r < 16; ++r) atomicAdd(&ws[WS_WFIN + r * 1024 + i], acc[r]);

  if (blk == 0 && t < 64) {
    float a2[16];
#pragma unroll
    for (int r = 0; r < 16; ++r) a2[r] = 0.f;
    for (int f = t; f < 512; f += 64) {
      float v = base_b[f];
#pragma unroll
      for (int r = 0; r < 16; ++r) a2[r] = fmaf(WEFF[r * 512 + f], v, a2[r]);
    }
#pragma unroll
    for (int m = 1; m <= 32; m <<= 1) {
#pragma unroll
      for (int r = 0; r < 16; ++r) a2[r] += __shfl_xor(a2[r], m, 64);
    }
    if (t == 0) {
#pragma unroll
      for (int r = 0; r < 16; ++r) atomicAdd(&ws[WS_BFIN + r], a2[r]);
    }
  }
}

__global__ __launch_bounds__(256) void k_out(const float* __restrict__ x,
                                             const float* __restrict__ ws,
                                             float* __restrict__ out) {
  __shared__ float4 wfs[4096];
  const int t = threadIdx.x;
  const float4* wf4 = (const float4*)(ws + WS_WFIN);
#pragma unroll
  for (int k = 0; k < 16; ++k) wfs[t + 256 * k] = wf4[t + 256 * k];
  __syncthreads();

  const int b0 = blockIdx.x * 16;
  const int bp = t >> 5;
  const int isub = t & 31;
  const int bA = b0 + bp * 2;
  const float* xa = x + (size_t)bA * 1024;
  const float* xb = xa + 1024;
  float acc0[16], acc1[16];
#pragma unroll
  for (int r = 0; r < 16; ++r) { acc0[r] = 0.f; acc1[r] = 0.f; }

  for (int chunk = 0; chunk < 4; ++chunk) {
#pragma unroll
    for (int j = 0; j < 2; ++j) {
      const int off = chunk * 256 + j * 128 + isub * 4;
      float4 xv0 = *(const float4*)&xa[off];
      float4 xv1 = *(const float4*)&xb[off];
      const float4* wrow = wfs + chunk * 64 + j * 32 + isub;
#pragma unroll
      for (int r = 0; r < 16; ++r) {
        float4 w = wrow[r * 256];
        acc0[r] += xv0.x * w.x + xv0.y * w.y + xv0.z * w.z + xv0.w * w.w;
        acc1[r] += xv1.x * w.x + xv1.y * w.y + xv1.z * w.z + xv1.w * w.w;
      }
    }
  }
#pragma unroll
  for (int m = 1; m <= 16; m <<= 1) {
#pragma unroll
    for (int r = 0; r < 16; ++r) {
      acc0[r] += __shfl_xor(acc0[r], m, 64);
      acc1[r] += __shfl_xor(acc1[r], m, 64);
    }
  }
  if (isub == 0) {
#pragma unroll
    for (int r = 0; r < 16; ++r) {
      float bf = ws[WS_BFIN + r];
      float v0 = acc0[r] + bf;
      float v1 = acc1[r] + bf;
      out[r * 4096 + bA] = 1.f / (1.f + expf(-v0));
      out[r * 4096 + bA + 1] = 1.f / (1.f + expf(-v1));
      out[65536 + r * 4096 + bA] = v0;
      out[65536 + r * 4096 + bA + 1] = v1;
    }
  }
}

extern "C" void kernel_launch(void* const* d_in, const int* in_sizes, int n_in,
                              void* d_out, int out_size, void* d_ws, size_t ws_size,
                              hipStream_t stream) {
  (void)in_sizes; (void)n_in; (void)out_size; (void)ws_size;
  const float* x      = (const float*)d_in[0];
  const float* pref   = (const float*)d_in[1];
  const float* base_w = (const float*)d_in[2];
  const float* base_b = (const float*)d_in[3];
  const float* wm1_w  = (const float*)d_in[4];
  const float* wm1_b  = (const float*)d_in[5];
  const float* wm2_w  = (const float*)d_in[6];
  const float* wm2_b  = (const float*)d_in[7];
  const float* ray0_w = (const float*)d_in[8];
  const float* ray0_b = (const float*)d_in[9];
  const float* ray2_w = (const float*)d_in[10];
  const float* ray2_b = (const float*)d_in[11];
  const float* fc1_w  = (const float*)d_in[12];
  const float* fc1_b  = (const float*)d_in[13];
  const float* b1_w   = (const float*)d_in[14];
  const float* b1_b   = (const float*)d_in[15];
  const float* fc2_w  = (const float*)d_in[16];
  const float* fc2_b  = (const float*)d_in[17];
  const float* b2_w   = (const float*)d_in[18];
  const float* b2_b   = (const float*)d_in[19];
  float* ws  = (float*)d_ws;
  float* out = (float*)d_out;

  static int g_mode = -1;
  if (g_mode < 0) {
    int maxb = 0;
    hipError_t e1 = hipOccupancyMaxActiveBlocksPerMultiprocessor(&maxb, k_all, 256, 0);
    int coop = 0, dev = 0;
    (void)hipGetDevice(&dev);
    hipError_t e2 = hipDeviceGetAttribute(&coop, hipDeviceAttributeCooperativeLaunch, dev);
    g_mode = (e1 == hipSuccess && maxb >= 2 && (e2 != hipSuccess || coop != 0)) ? 1 : 0;
  }

  if (g_mode == 1) {
    void* args[] = {
        (void*)&x, (void*)&pref, (void*)&base_w, (void*)&base_b,
        (void*)&wm1_w, (void*)&wm1_b, (void*)&wm2_w, (void*)&wm2_b,
        (void*)&ray0_w, (void*)&ray0_b, (void*)&ray2_w, (void*)&ray2_b,
        (void*)&fc1_w, (void*)&fc1_b, (void*)&b1_w, (void*)&b1_b,
        (void*)&fc2_w, (void*)&fc2_b, (void*)&b2_w, (void*)&b2_b,
        (void*)&ws, (void*)&out};
    hipError_t e = hipLaunchCooperativeKernel(k_all, dim3(512), dim3(256), args, 0, stream);
    if (e == hipSuccess) return;
    g_mode = 0;  // fall through to legacy path
  }

  hipMemsetAsync(ws + WS_ZERO_BEG, 0, (size_t)WS_ZERO_CNT * sizeof(float), stream);
  k_stage1<<<80, 256, 0, stream>>>(pref, wm1_w, wm1_b, wm2_w, wm2_b,
                                   ray0_w, ray0_b, ray2_w, ray2_b, fc2_b, ws);
  k_stage2<<<80, 256, 0, stream>>>(fc2_w, ws);
  k_main<<<2073, 256, 0, stream>>>(fc1_w, fc1_b, b1_w, b1_b, b2_w, b2_b, ws);
  k_wfin<<<128, 256, 0, stream>>>(base_w, base_b, ws);
  k_out<<<256, 256, 0, stream>>>(x, ws, out);
}